// Round 3
// baseline (220.585 us; speedup 1.0000x reference)
//
#include <hip/hip_runtime.h>

// LearnerC aggregator:
//   out[n] = relu( concat(g_emb[g[nodes[n]]], a_emb[a[nodes[n]]], u_emb[nodes[n]]) @ W.T + b )
//
// Optimizations:
//  - gender/age have only 2*8=16 combos -> fold b + e_g@Wg.T + e_a@Wa.T into a
//    16x32 GA table per block (LDS), leaving only the 32x32 u@Wu.T per node.
//  - one thread == one node; Wu reads are uniform-address -> scalar loads that
//    feed v_fmac's SGPR operand; u row is 8x float4 (128B fully consumed).
//  - node/gender/age/u gathers issued BEFORE the staging barriers so their
//    L2/L3 latency hides under the GA-table setup compute.
//  - non-temporal output stores: don't evict the L3-resident u_emb (128MB).

#define NNODES   131072
#define BLOCK    256
#define SWS      68   // padded LDS stride for W[:,0:64] rows (float4-aligned; 4-way worst)

typedef float floatx4 __attribute__((ext_vector_type(4)));  // clang vector: ok for nontemporal builtin

__global__ __launch_bounds__(BLOCK) void learnerc_agg_kernel(
    const int*   __restrict__ nodes,
    const int*   __restrict__ gender,
    const int*   __restrict__ age,
    const float* __restrict__ u_emb,
    const float* __restrict__ g_emb,
    const float* __restrict__ a_emb,
    const float* __restrict__ W,     // [32][96] row-major
    const float* __restrict__ b,     // [32]
    float*       __restrict__ out)   // [NNODES][32]
{
    __shared__ float sW[32 * SWS];   // W[d][k], k in [0,64)
    __shared__ float sGA[32 * 16];   // transposed: [d][ga] -> conflict-free gather
    __shared__ float sG[64];
    __shared__ float sA[256];
    __shared__ float sB[32];

    const int t = threadIdx.x;
    const int n = blockIdx.x * BLOCK + t;

    // ---- issue the dependent gather chain EARLY (overlaps setup below) ----
    const int node = nodes[n];
    const int g_of_n = gender[node];
    const int a_of_n = age[node];
    float u[32];
    {
        const float* up = u_emb + (size_t)node * 32;
        #pragma unroll
        for (int j = 0; j < 8; ++j) {
            const floatx4 v = *reinterpret_cast<const floatx4*>(up + j * 4);
            u[j * 4 + 0] = v.x; u[j * 4 + 1] = v.y;
            u[j * 4 + 2] = v.z; u[j * 4 + 3] = v.w;
        }
    }

    // ---- stage W[:,0:64] (2048 floats) + small tables into LDS ----
    for (int c = t; c < 512; c += BLOCK) {
        const int d  = c >> 4;          // 16 float4 per 64-wide row
        const int k4 = (c & 15) << 2;
        const floatx4 v = *reinterpret_cast<const floatx4*>(W + d * 96 + k4);
        *reinterpret_cast<floatx4*>(&sW[d * SWS + k4]) = v;
    }
    if (t < 64) sG[t] = g_emb[t];
    sA[t] = a_emb[t];                   // 256 elements == blockDim
    if (t < 32) sB[t] = b[t];
    __syncthreads();

    // ---- GA[ga][d] = b[d] + g_emb[g]·W[d,0:32] + a_emb[a]·W[d,32:64] ----
    for (int e = t; e < 512; e += BLOCK) {
        const int ga = e >> 5;
        const int d  = e & 31;
        const int g  = ga >> 3;
        const int aa = ga & 7;
        float acc = sB[d];
        #pragma unroll
        for (int k = 0; k < 32; ++k)
            acc += sG[g * 32 + k] * sW[d * SWS + k];
        #pragma unroll
        for (int k = 0; k < 32; ++k)
            acc += sA[aa * 32 + k] * sW[d * SWS + 32 + k];
        sGA[d * 16 + ga] = acc;         // transposed store
    }
    __syncthreads();

    // ---- main: 32x32 u @ Wu.T per node ----
    const int ga = g_of_n * 8 + a_of_n;
    const float* Wu = W + 64;           // W[d][64+k] -> Wu[d*96+k], uniform addr
    float* op = out + (size_t)n * 32;

    #pragma unroll
    for (int d4 = 0; d4 < 8; ++d4) {
        float rr[4];
        #pragma unroll
        for (int j = 0; j < 4; ++j) {
            const int d = d4 * 4 + j;
            float s = sGA[d * 16 + ga];             // <=16 distinct addrs, 16 banks
            #pragma unroll
            for (int k = 0; k < 32; ++k)
                s += u[k] * Wu[d * 96 + k];         // uniform -> s_load + v_fmac(sgpr)
            rr[j] = fmaxf(s, 0.0f);
        }
        floatx4 r; r.x = rr[0]; r.y = rr[1]; r.z = rr[2]; r.w = rr[3];
        __builtin_nontemporal_store(r, reinterpret_cast<floatx4*>(op + d4 * 4));
    }
}

extern "C" void kernel_launch(void* const* d_in, const int* in_sizes, int n_in,
                              void* d_out, int out_size, void* d_ws, size_t ws_size,
                              hipStream_t stream) {
    const int*   nodes  = (const int*)  d_in[0];
    const int*   gender = (const int*)  d_in[1];
    const int*   age    = (const int*)  d_in[2];
    const float* u_emb  = (const float*)d_in[3];
    const float* g_emb  = (const float*)d_in[4];
    const float* a_emb  = (const float*)d_in[5];
    const float* W      = (const float*)d_in[6];
    const float* b      = (const float*)d_in[7];
    float*       out    = (float*)d_out;

    const int grid = NNODES / BLOCK;    // 131072 / 256 = 512
    learnerc_agg_kernel<<<grid, BLOCK, 0, stream>>>(
        nodes, gender, age, u_emb, g_emb, a_emb, W, b, out);
}

// Round 10
// 196.844 us; speedup vs baseline: 1.1206x; 1.1206x over previous
//
#include <hip/hip_runtime.h>

// LearnerC aggregator: out[n] = relu(concat(g_emb[g], a_emb[a], u_emb[node]) @ W.T + b)
//
// Structure (round 6..9):
//  - setup kernel (3 blocks, runs once per launch): GA[16][32] =
//    b + g_emb@Wg.T + a_emb@Wa.T (only 2*8=16 gender/age combos) and
//    Wu transposed -> WuT[32][32] (k-major), both into d_ws.
//  - main kernel: 4 threads per node-slice (dq=t&3 owns 8 outputs),
//    2 nodes per thread (halves LDS instr issue: W slice read once serves
//    2 nodes). 1024 blocks = 4 blocks/CU at (256,4) = one full-residency
//    pass, 16 waves/CU for gather-latency hiding. Per thread: 64 broadcast
//    conflict-free ds_read_b128 + 512 VALU FMAs for 2 nodes.
//  - launch_bounds (256,4): 128-VGPR cap, no spill risk at ~100 VGPR est.

#define NNODES   131072
#define BLOCK    256
#define NPB      128     // nodes per block (4 threads/node-slice, 2 nodes/thread)

typedef float floatx4 __attribute__((ext_vector_type(4)));

// ---------------- setup: GA table + Wu transpose (tiny, 3 blocks) ----------------
__global__ __launch_bounds__(BLOCK) void learnerc_setup_kernel(
    const float* __restrict__ g_emb,   // [2][32]
    const float* __restrict__ a_emb,   // [8][32]
    const float* __restrict__ W,       // [32][96]
    const float* __restrict__ b,       // [32]
    float*       __restrict__ ws)      // [0:1024) WuT, [1024:1536) GA
{
    float* wuT = ws;                   // WuT[k][d] = W[d][64+k]
    float* gaT = ws + 1024;            // GA[ga][d]
    const int t = threadIdx.x;

    if (blockIdx.x == 0) {
        #pragma unroll
        for (int c = t; c < 1024; c += BLOCK) {
            const int d = c >> 5;
            const int k = c & 31;
            wuT[k * 32 + d] = W[d * 96 + 64 + k];   // read coalesced over k
        }
    } else {
        const int idx = (blockIdx.x - 1) * BLOCK + t;   // [0,512)
        const int ga  = idx >> 5;
        const int d   = idx & 31;
        const int g   = ga >> 3;
        const int a   = ga & 7;
        const float* wr = W + d * 96;
        float acc = b[d];
        #pragma unroll
        for (int k = 0; k < 32; ++k) acc += g_emb[g * 32 + k] * wr[k];
        #pragma unroll
        for (int k = 0; k < 32; ++k) acc += a_emb[a * 32 + k] * wr[32 + k];
        gaT[ga * 32 + d] = acc;
    }
}

// ---------------- main: 4 threads per node-slice, 2 nodes per thread ----------------
__global__ __launch_bounds__(BLOCK, 4) void learnerc_agg_kernel(
    const int*   __restrict__ nodes,
    const int*   __restrict__ gender,
    const int*   __restrict__ age,
    const float* __restrict__ u_emb,
    const float* __restrict__ ws,      // WuT + GA from setup
    float*       __restrict__ out)     // [NNODES][32]
{
    __shared__ float sWuT[1024];       // [k][d], k-major: broadcast-read layout

    const int t    = threadIdx.x;
    const int dq   = t & 3;            // which 8-output slice of d
    const int slot = t >> 2;           // 0..63
    const int n0   = blockIdx.x * NPB + slot;
    const int n1   = n0 + 64;

    // ---- issue dependent gather chains early (overlap staging below) ----
    const int node0 = nodes[n0];
    const int node1 = nodes[n1];
    const int gg0 = gender[node0], aa0 = age[node0];
    const int gg1 = gender[node1], aa1 = age[node1];

    float u0[32], u1[32];
    {
        const float* up0 = u_emb + (size_t)node0 * 32;
        const float* up1 = u_emb + (size_t)node1 * 32;
        #pragma unroll
        for (int j = 0; j < 8; ++j) {
            const floatx4 v = *reinterpret_cast<const floatx4*>(up0 + j * 4);
            u0[j * 4 + 0] = v.x; u0[j * 4 + 1] = v.y;
            u0[j * 4 + 2] = v.z; u0[j * 4 + 3] = v.w;
        }
        #pragma unroll
        for (int j = 0; j < 8; ++j) {
            const floatx4 v = *reinterpret_cast<const floatx4*>(up1 + j * 4);
            u1[j * 4 + 0] = v.x; u1[j * 4 + 1] = v.y;
            u1[j * 4 + 2] = v.z; u1[j * 4 + 3] = v.w;
        }
    }

    // ---- stage WuT: one float4 per thread (coalesced read, full-bw LDS write) ----
    reinterpret_cast<floatx4*>(sWuT)[t] = reinterpret_cast<const floatx4*>(ws)[t];
    __syncthreads();

    // ---- GA contributions: 2KB L1/L2-resident table ----
    const float* gaBase = ws + 1024;
    float acc0[8], acc1[8];
    {
        const float* g0 = gaBase + (gg0 * 8 + aa0) * 32 + dq * 8;
        const floatx4 c0 = *reinterpret_cast<const floatx4*>(g0);
        const floatx4 c1 = *reinterpret_cast<const floatx4*>(g0 + 4);
        acc0[0] = c0.x; acc0[1] = c0.y; acc0[2] = c0.z; acc0[3] = c0.w;
        acc0[4] = c1.x; acc0[5] = c1.y; acc0[6] = c1.z; acc0[7] = c1.w;
        const float* g1 = gaBase + (gg1 * 8 + aa1) * 32 + dq * 8;
        const floatx4 d0 = *reinterpret_cast<const floatx4*>(g1);
        const floatx4 d1 = *reinterpret_cast<const floatx4*>(g1 + 4);
        acc1[0] = d0.x; acc1[1] = d0.y; acc1[2] = d0.z; acc1[3] = d0.w;
        acc1[4] = d1.x; acc1[5] = d1.y; acc1[6] = d1.z; acc1[7] = d1.w;
    }

    // ---- 8x32 slices of u @ Wu.T for BOTH nodes per W read:
    //      2 b128 LDS reads per k (4 distinct addrs -> 16-lane broadcast,
    //      conflict-free), 16 FMAs per k ----
    const float* wbase = sWuT + dq * 8;
    #pragma unroll
    for (int k = 0; k < 32; ++k) {
        const floatx4 wlo = *reinterpret_cast<const floatx4*>(wbase + k * 32);
        const floatx4 whi = *reinterpret_cast<const floatx4*>(wbase + k * 32 + 4);
        const float uk0 = u0[k];
        const float uk1 = u1[k];
        acc0[0] += uk0 * wlo.x; acc0[1] += uk0 * wlo.y;
        acc0[2] += uk0 * wlo.z; acc0[3] += uk0 * wlo.w;
        acc0[4] += uk0 * whi.x; acc0[5] += uk0 * whi.y;
        acc0[6] += uk0 * whi.z; acc0[7] += uk0 * whi.w;
        acc1[0] += uk1 * wlo.x; acc1[1] += uk1 * wlo.y;
        acc1[2] += uk1 * wlo.z; acc1[3] += uk1 * wlo.w;
        acc1[4] += uk1 * whi.x; acc1[5] += uk1 * whi.y;
        acc1[6] += uk1 * whi.z; acc1[7] += uk1 * whi.w;
    }

    // ---- relu + store (4x b128; contiguous 1KB per wave instruction) ----
    float* op0 = out + (size_t)n0 * 32 + dq * 8;
    float* op1 = out + (size_t)n1 * 32 + dq * 8;
    floatx4 r;
    r.x = fmaxf(acc0[0], 0.f); r.y = fmaxf(acc0[1], 0.f);
    r.z = fmaxf(acc0[2], 0.f); r.w = fmaxf(acc0[3], 0.f);
    *reinterpret_cast<floatx4*>(op0) = r;
    r.x = fmaxf(acc0[4], 0.f); r.y = fmaxf(acc0[5], 0.f);
    r.z = fmaxf(acc0[6], 0.f); r.w = fmaxf(acc0[7], 0.f);
    *reinterpret_cast<floatx4*>(op0 + 4) = r;
    r.x = fmaxf(acc1[0], 0.f); r.y = fmaxf(acc1[1], 0.f);
    r.z = fmaxf(acc1[2], 0.f); r.w = fmaxf(acc1[3], 0.f);
    *reinterpret_cast<floatx4*>(op1) = r;
    r.x = fmaxf(acc1[4], 0.f); r.y = fmaxf(acc1[5], 0.f);
    r.z = fmaxf(acc1[6], 0.f); r.w = fmaxf(acc1[7], 0.f);
    *reinterpret_cast<floatx4*>(op1 + 4) = r;
}

extern "C" void kernel_launch(void* const* d_in, const int* in_sizes, int n_in,
                              void* d_out, int out_size, void* d_ws, size_t ws_size,
                              hipStream_t stream) {
    const int*   nodes  = (const int*)  d_in[0];
    const int*   gender = (const int*)  d_in[1];
    const int*   age    = (const int*)  d_in[2];
    const float* u_emb  = (const float*)d_in[3];
    const float* g_emb  = (const float*)d_in[4];
    const float* a_emb  = (const float*)d_in[5];
    const float* W      = (const float*)d_in[6];
    const float* b      = (const float*)d_in[7];
    float*       out    = (float*)d_out;
    float*       ws     = (float*)d_ws;

    learnerc_setup_kernel<<<3, BLOCK, 0, stream>>>(g_emb, a_emb, W, b, ws);

    const int grid = NNODES / NPB;     // 1024 blocks = 4/CU, one residency pass
    learnerc_agg_kernel<<<grid, BLOCK, 0, stream>>>(
        nodes, gender, age, u_emb, ws, out);
}

// Round 13
// 195.773 us; speedup vs baseline: 1.1267x; 1.0055x over previous
//
#include <hip/hip_runtime.h>

// LearnerC aggregator: out[n] = relu(concat(g_emb[g], a_emb[a], u_emb[node]) @ W.T + b)
//
// Structure (round 11..13):
//  - setup kernel (3 blocks): GA[16][32] = b + g_emb@Wg.T + a_emb@Wa.T
//    (only 2*8=16 combos) and Wu -> WuT[32][32] (k-major) into d_ws.
//  - main kernel: 4 threads per node-slice (dq owns 8 outputs),
//    4 nodes per thread: each ds_read_b128 of WuT serves 4 nodes
//    (16 LDS instr/node, was 32). floatx4 vector math -> v_pk_fma_f32.
//    512 blocks = 2/CU at (256,2): 256-VGPR cap (est ~185, no spill).

#define NNODES   131072
#define BLOCK    256
#define NPB      256     // nodes per block (4 threads/node-slice, 4 nodes/thread)

typedef float floatx4 __attribute__((ext_vector_type(4)));

// ---------------- setup: GA table + Wu transpose (tiny, 3 blocks) ----------------
__global__ __launch_bounds__(BLOCK) void learnerc_setup_kernel(
    const float* __restrict__ g_emb,   // [2][32]
    const float* __restrict__ a_emb,   // [8][32]
    const float* __restrict__ W,       // [32][96]
    const float* __restrict__ b,       // [32]
    float*       __restrict__ ws)      // [0:1024) WuT, [1024:1536) GA
{
    float* wuT = ws;                   // WuT[k][d] = W[d][64+k]
    float* gaT = ws + 1024;            // GA[ga][d]
    const int t = threadIdx.x;

    if (blockIdx.x == 0) {
        #pragma unroll
        for (int c = t; c < 1024; c += BLOCK) {
            const int d = c >> 5;
            const int k = c & 31;
            wuT[k * 32 + d] = W[d * 96 + 64 + k];   // read coalesced over k
        }
    } else {
        const int idx = (blockIdx.x - 1) * BLOCK + t;   // [0,512)
        const int ga  = idx >> 5;
        const int d   = idx & 31;
        const int g   = ga >> 3;
        const int a   = ga & 7;
        const float* wr = W + d * 96;
        float acc = b[d];
        #pragma unroll
        for (int k = 0; k < 32; ++k) acc += g_emb[g * 32 + k] * wr[k];
        #pragma unroll
        for (int k = 0; k < 32; ++k) acc += a_emb[a * 32 + k] * wr[32 + k];
        gaT[ga * 32 + d] = acc;
    }
}

// ---------------- main: 4 threads per node-slice, 4 nodes per thread ----------------
__global__ __launch_bounds__(BLOCK, 2) void learnerc_agg_kernel(
    const int*   __restrict__ nodes,
    const int*   __restrict__ gender,
    const int*   __restrict__ age,
    const float* __restrict__ u_emb,
    const float* __restrict__ ws,      // WuT + GA from setup
    float*       __restrict__ out)     // [NNODES][32]
{
    __shared__ float sWuT[1024];       // [k][d], k-major broadcast-read layout

    const int t    = threadIdx.x;
    const int dq   = t & 3;            // which 8-output slice of d
    const int slot = t >> 2;           // 0..63
    const int base = blockIdx.x * NPB + slot;

    // ---- issue dependent gather chains early (overlap staging below) ----
    const int nodeA = nodes[base];
    const int nodeB = nodes[base + 64];
    const int nodeC = nodes[base + 128];
    const int nodeD = nodes[base + 192];
    const int gaA = gender[nodeA] * 8 + age[nodeA];
    const int gaB = gender[nodeB] * 8 + age[nodeB];
    const int gaC = gender[nodeC] * 8 + age[nodeC];
    const int gaD = gender[nodeD] * 8 + age[nodeD];

    floatx4 uA[8], uB[8], uC[8], uD[8];   // full 128B rows, static indexing only
    {
        const float* pA = u_emb + (size_t)nodeA * 32;
        const float* pB = u_emb + (size_t)nodeB * 32;
        const float* pC = u_emb + (size_t)nodeC * 32;
        const float* pD = u_emb + (size_t)nodeD * 32;
        #pragma unroll
        for (int j = 0; j < 8; ++j) uA[j] = *reinterpret_cast<const floatx4*>(pA + j * 4);
        #pragma unroll
        for (int j = 0; j < 8; ++j) uB[j] = *reinterpret_cast<const floatx4*>(pB + j * 4);
        #pragma unroll
        for (int j = 0; j < 8; ++j) uC[j] = *reinterpret_cast<const floatx4*>(pC + j * 4);
        #pragma unroll
        for (int j = 0; j < 8; ++j) uD[j] = *reinterpret_cast<const floatx4*>(pD + j * 4);
    }

    // ---- stage WuT: one float4 per thread ----
    reinterpret_cast<floatx4*>(sWuT)[t] = reinterpret_cast<const floatx4*>(ws)[t];
    __syncthreads();

    // ---- GA contributions (2KB L1/L2-resident table) ----
    const float* gaBase = ws + 1024;
    floatx4 accAlo = *reinterpret_cast<const floatx4*>(gaBase + gaA * 32 + dq * 8);
    floatx4 accAhi = *reinterpret_cast<const floatx4*>(gaBase + gaA * 32 + dq * 8 + 4);
    floatx4 accBlo = *reinterpret_cast<const floatx4*>(gaBase + gaB * 32 + dq * 8);
    floatx4 accBhi = *reinterpret_cast<const floatx4*>(gaBase + gaB * 32 + dq * 8 + 4);
    floatx4 accClo = *reinterpret_cast<const floatx4*>(gaBase + gaC * 32 + dq * 8);
    floatx4 accChi = *reinterpret_cast<const floatx4*>(gaBase + gaC * 32 + dq * 8 + 4);
    floatx4 accDlo = *reinterpret_cast<const floatx4*>(gaBase + gaD * 32 + dq * 8);
    floatx4 accDhi = *reinterpret_cast<const floatx4*>(gaBase + gaD * 32 + dq * 8 + 4);

    // ---- 8x32 slices of u @ Wu.T for 4 nodes per W read:
    //      2 b128 LDS reads per k serve 4 nodes (broadcast, conflict-free);
    //      vector FMAs -> v_pk_fma_f32 ----
    const float* wbase = sWuT + dq * 8;
    #pragma unroll
    for (int k = 0; k < 32; ++k) {
        const floatx4 wlo = *reinterpret_cast<const floatx4*>(wbase + k * 32);
        const floatx4 whi = *reinterpret_cast<const floatx4*>(wbase + k * 32 + 4);
        const float ukA = uA[k >> 2][k & 3];   // static after unroll
        const float ukB = uB[k >> 2][k & 3];
        const float ukC = uC[k >> 2][k & 3];
        const float ukD = uD[k >> 2][k & 3];
        accAlo += wlo * ukA;  accAhi += whi * ukA;
        accBlo += wlo * ukB;  accBhi += whi * ukB;
        accClo += wlo * ukC;  accChi += whi * ukC;
        accDlo += wlo * ukD;  accDhi += whi * ukD;
    }

    // ---- relu + store (8x b128; contiguous per wave) ----
    float* opA = out + (size_t)(base)       * 32 + dq * 8;
    float* opB = out + (size_t)(base + 64)  * 32 + dq * 8;
    float* opC = out + (size_t)(base + 128) * 32 + dq * 8;
    float* opD = out + (size_t)(base + 192) * 32 + dq * 8;
    floatx4 r;
    #define RELU4(v) { r.x = fmaxf((v).x, 0.f); r.y = fmaxf((v).y, 0.f); \
                       r.z = fmaxf((v).z, 0.f); r.w = fmaxf((v).w, 0.f); }
    RELU4(accAlo); *reinterpret_cast<floatx4*>(opA)     = r;
    RELU4(accAhi); *reinterpret_cast<floatx4*>(opA + 4) = r;
    RELU4(accBlo); *reinterpret_cast<floatx4*>(opB)     = r;
    RELU4(accBhi); *reinterpret_cast<floatx4*>(opB + 4) = r;
    RELU4(accClo); *reinterpret_cast<floatx4*>(opC)     = r;
    RELU4(accChi); *reinterpret_cast<floatx4*>(opC + 4) = r;
    RELU4(accDlo); *reinterpret_cast<floatx4*>(opD)     = r;
    RELU4(accDhi); *reinterpret_cast<floatx4*>(opD + 4) = r;
    #undef RELU4
}

extern "C" void kernel_launch(void* const* d_in, const int* in_sizes, int n_in,
                              void* d_out, int out_size, void* d_ws, size_t ws_size,
                              hipStream_t stream) {
    const int*   nodes  = (const int*)  d_in[0];
    const int*   gender = (const int*)  d_in[1];
    const int*   age    = (const int*)  d_in[2];
    const float* u_emb  = (const float*)d_in[3];
    const float* g_emb  = (const float*)d_in[4];
    const float* a_emb  = (const float*)d_in[5];
    const float* W      = (const float*)d_in[6];
    const float* b      = (const float*)d_in[7];
    float*       out    = (float*)d_out;
    float*       ws     = (float*)d_ws;

    learnerc_setup_kernel<<<3, BLOCK, 0, stream>>>(g_emb, a_emb, W, b, ws);

    const int grid = NNODES / NPB;     // 512 blocks = 2/CU residency
    learnerc_agg_kernel<<<grid, BLOCK, 0, stream>>>(
        nodes, gender, age, u_emb, ws, out);
}